// Round 2
// baseline (194.701 us; speedup 1.0000x reference)
//
#include <hip/hip_runtime.h>
#include <cstddef>

// JastrowNet: B=512, n_elec=32 (16 up/16 down), n_atoms=8, dist_feat=32,
// kernel=8, embed=16, layers=2, w-hidden=16.
// One block (512 threads) per batch element, both layers fused.
// Key layout: electron pairs processed in 16x16 spin quadrants so the filter
// channel (same/anti) is uniform across the whole block per iteration ->
// weight reads from LDS are pure broadcast (no bank conflicts).
// z[i,k] = sum_j w[i,j,k]*hx[j,k] is reduced in-register via 16-lane
// shuffles; no w tensor is ever materialized in LDS.

#define NB   512
#define NE   32
#define NA   8
#define NF   32
#define NH   16
#define NK   8
#define NEMB 16
#define NL   2

__device__ __forceinline__ float ssp(float v){
    // shifted softplus: log(1+exp(v)) - log(2), overflow-safe
    return fmaxf(v, 0.f) + __logf(1.f + __expf(-fabsf(v))) - 0.6931471805599453f;
}

// One edge row (32 features) through the 32->16->8 ssp MLP.
// Weights/biases are LDS pointers; with block-uniform channel these reads are
// wave-broadcast (single address) -> conflict-free.
__device__ __forceinline__ void compute_w(const float4 ev[8],
        const float* __restrict__ sW1, const float* __restrict__ sB1,
        const float* __restrict__ sW2, const float* __restrict__ sB2,
        float w[NK])
{
    float h1[NH];
#pragma unroll
    for (int h = 0; h < NH; h++) h1[h] = sB1[h];
#pragma unroll
    for (int q = 0; q < 8; q++){
        float e4[4] = {ev[q].x, ev[q].y, ev[q].z, ev[q].w};
#pragma unroll
        for (int c = 0; c < 4; c++){
            const float ef = e4[c];
            const float4* w4 = (const float4*)(sW1 + (4*q + c)*NH);
#pragma unroll
            for (int t = 0; t < 4; t++){
                float4 wv = w4[t];
                h1[4*t+0] = fmaf(ef, wv.x, h1[4*t+0]);
                h1[4*t+1] = fmaf(ef, wv.y, h1[4*t+1]);
                h1[4*t+2] = fmaf(ef, wv.z, h1[4*t+2]);
                h1[4*t+3] = fmaf(ef, wv.w, h1[4*t+3]);
            }
        }
    }
#pragma unroll
    for (int h = 0; h < NH; h++) h1[h] = ssp(h1[h]);
    float acc[NK];
#pragma unroll
    for (int k = 0; k < NK; k++) acc[k] = sB2[k];
#pragma unroll
    for (int h = 0; h < NH; h++){
        const float hv = h1[h];
        const float4* w4 = (const float4*)(sW2 + h*NK);
#pragma unroll
        for (int t = 0; t < 2; t++){
            float4 wv = w4[t];
            acc[4*t+0] = fmaf(hv, wv.x, acc[4*t+0]);
            acc[4*t+1] = fmaf(hv, wv.y, acc[4*t+1]);
            acc[4*t+2] = fmaf(hv, wv.z, acc[4*t+2]);
            acc[4*t+3] = fmaf(hv, wv.w, acc[4*t+3]);
        }
    }
#pragma unroll
    for (int k = 0; k < NK; k++) w[k] = ssp(acc[k]);
}

extern "C" __global__ void __launch_bounds__(512, 4)
jastrow_kernel(const float* __restrict__ edges_elec,
               const float* __restrict__ edges_nuc,
               const float* __restrict__ X_emb,
               const float* __restrict__ Yk,
               const float* __restrict__ wW1, const float* __restrict__ wb1,
               const float* __restrict__ wW2, const float* __restrict__ wb2,
               const float* __restrict__ hW,  const float* __restrict__ hb,
               const float* __restrict__ gW,  const float* __restrict__ gb,
               const float* __restrict__ orbW,
               float* __restrict__ out)
{
    __shared__ __align__(16) float s_wW1[NL*3*NF*NH];   // 12 KB
    __shared__ __align__(16) float s_wb1[NL*3*NH];
    __shared__ __align__(16) float s_wW2[NL*3*NH*NK];   // 3 KB
    __shared__ __align__(16) float s_wb2[NL*3*NK];
    __shared__ float s_hW[NL*NEMB*NK];
    __shared__ float s_hb[NL*NK];
    __shared__ float s_gW[NL*NK*NEMB];
    __shared__ float s_gb[NL*NEMB];
    __shared__ __align__(16) float s_Y[NA*NK];
    __shared__ float s_orb[NEMB];
    __shared__ float s_x[NE*NEMB];                      // 2 KB
    __shared__ __align__(16) float s_hx[NE*NK];
    __shared__ float s_z[NE*NK];
    __shared__ float s_red[8];

    const int b   = blockIdx.x;
    const int tid = threadIdx.x;

    // ---- stage all weights into LDS ----
    for (int i2 = tid; i2 < NL*3*NF*NH; i2 += 512) s_wW1[i2] = wW1[i2];
    for (int i2 = tid; i2 < NL*3*NH;    i2 += 512) s_wb1[i2] = wb1[i2];
    for (int i2 = tid; i2 < NL*3*NH*NK; i2 += 512) s_wW2[i2] = wW2[i2];
    for (int i2 = tid; i2 < NL*3*NK;    i2 += 512) s_wb2[i2] = wb2[i2];
    for (int i2 = tid; i2 < NL*NEMB*NK; i2 += 512) s_hW[i2]  = hW[i2];
    for (int i2 = tid; i2 < NL*NK;      i2 += 512) s_hb[i2]  = hb[i2];
    for (int i2 = tid; i2 < NL*NK*NEMB; i2 += 512) s_gW[i2]  = gW[i2];
    for (int i2 = tid; i2 < NL*NEMB;    i2 += 512) s_gb[i2]  = gb[i2];
    for (int i2 = tid; i2 < NA*NK;      i2 += 512) s_Y[i2]   = Yk[i2];
    for (int i2 = tid; i2 < NEMB;       i2 += 512) s_orb[i2] = orbW[i2];
    // initial embeddings by spin (i<16 -> up, else down)
    if (tid < NE*NEMB){
        int row = tid >> 4; int spin = row >> 4;
        s_x[tid] = X_emb[spin*NEMB + (tid & 15)];
    }
    __syncthreads();

    // quadrant mapping: qh = this thread's spin half for i; i16/j16 in [0,16)
    const int qh  = tid >> 8;
    const int i16 = (tid >> 4) & 15;
    const int j16 = tid & 15;
    const int iRow = qh*16 + i16;

    const float* base_e = edges_elec + (size_t)b * NE*NE*NF;
    const float* base_n = edges_nuc  + (size_t)b * NE*NA*NF;

    const int r0 = iRow*NE + qh*16     + j16;   // same-spin partner row
    const int r1 = iRow*NE + (1-qh)*16 + j16;   // anti-spin partner row

    for (int l = 0; l < NL; l++){
        // issue same-spin edge load early
        float4 ev0[8];
        {
            const float4* p = (const float4*)(base_e + (size_t)r0 * NF);
#pragma unroll
            for (int q = 0; q < 8; q++) ev0[q] = p[q];
        }
        // ---- hx = ssp(x @ hW + hb) ----
        if (tid < NE*NK){
            int i = tid >> 3, k = tid & 7;
            float acc = s_hb[l*NK + k];
#pragma unroll
            for (int e = 0; e < NEMB; e++)
                acc = fmaf(s_x[i*NEMB + e], s_hW[(l*NEMB + e)*NK + k], acc);
            s_hx[tid] = ssp(acc);
        }
        __syncthreads();

        float zacc[NK];
        float4 ev1[8];
        {
            const float4* p = (const float4*)(base_e + (size_t)r1 * NF);
#pragma unroll
            for (int q = 0; q < 8; q++) ev1[q] = p[q];
        }
        // ---- same-spin quadrants (channel 0 uniform across block) ----
        {
            float w[NK];
            compute_w(ev0, &s_wW1[(l*3+0)*NF*NH], &s_wb1[(l*3+0)*NH],
                      &s_wW2[(l*3+0)*NH*NK], &s_wb2[(l*3+0)*NK], w);
            const float msk = (i16 == j16) ? 0.f : 1.f;   // exclude diagonal
            const float* hx = &s_hx[(qh*16 + j16)*NK];
            float p[NK];
#pragma unroll
            for (int k = 0; k < NK; k++) p[k] = w[k] * msk * hx[k];
#pragma unroll
            for (int off = 8; off > 0; off >>= 1)
#pragma unroll
                for (int k = 0; k < NK; k++) p[k] += __shfl_down(p[k], off, 16);
#pragma unroll
            for (int k = 0; k < NK; k++) zacc[k] = p[k];
        }
        // prefetch nuclear row (threads 0..255: i=tid>>3, m=tid&7 -> row tid)
        float4 evn[8];
        if (tid < NE*NA){
            const float4* p = (const float4*)(base_n + (size_t)tid * NF);
#pragma unroll
            for (int q = 0; q < 8; q++) evn[q] = p[q];
        }
        // ---- anti-spin quadrants (channel 1 uniform across block) ----
        {
            float w[NK];
            compute_w(ev1, &s_wW1[(l*3+1)*NF*NH], &s_wb1[(l*3+1)*NH],
                      &s_wW2[(l*3+1)*NH*NK], &s_wb2[(l*3+1)*NK], w);
            const float* hx = &s_hx[((1-qh)*16 + j16)*NK];
            float p[NK];
#pragma unroll
            for (int k = 0; k < NK; k++) p[k] = w[k] * hx[k];
#pragma unroll
            for (int off = 8; off > 0; off >>= 1)
#pragma unroll
                for (int k = 0; k < NK; k++) p[k] += __shfl_down(p[k], off, 16);
#pragma unroll
            for (int k = 0; k < NK; k++) zacc[k] += p[k];
        }
        // lane j16==0 holds z_elec[iRow,:] -> store (overwrite) to LDS
        if (j16 == 0){
            float* z = &s_z[iRow*NK];
#pragma unroll
            for (int k = 0; k < NK; k++) z[k] = zacc[k];
        }
        // ---- nuclear channel (channel 2 uniform) ----
        float nacc[NK];
        if (tid < NE*NA){
            float w[NK];
            compute_w(evn, &s_wW1[(l*3+2)*NF*NH], &s_wb1[(l*3+2)*NH],
                      &s_wW2[(l*3+2)*NH*NK], &s_wb2[(l*3+2)*NK], w);
            const float* Yr = &s_Y[(tid & 7)*NK];
            float p[NK];
#pragma unroll
            for (int k = 0; k < NK; k++) p[k] = w[k] * Yr[k];
#pragma unroll
            for (int off = 4; off > 0; off >>= 1)
#pragma unroll
                for (int k = 0; k < NK; k++) p[k] += __shfl_down(p[k], off, 8);
#pragma unroll
            for (int k = 0; k < NK; k++) nacc[k] = p[k];
        }
        __syncthreads();   // elec z stores visible
        if (tid < NE*NA && (tid & 7) == 0){
            float* z = &s_z[(tid >> 3)*NK];
#pragma unroll
            for (int k = 0; k < NK; k++) z[k] += nacc[k];
        }
        __syncthreads();   // s_z complete
        // ---- x += z @ gW + gb (one (i,e) per thread) ----
        {
            int i = tid >> 4, e = tid & 15;
            float acc = s_gb[l*NEMB + e];
#pragma unroll
            for (int k = 0; k < NK; k++)
                acc = fmaf(s_z[i*NK + k], s_gW[(l*NK + k)*NEMB + e], acc);
            s_x[tid] += acc;
        }
        __syncthreads();   // s_x ready for next layer / readout
    }

    // ---- readout: out[b] = sum_{i,e} x[i,e]*orbW[e] ----
    float part = s_x[tid] * s_orb[tid & 15];
#pragma unroll
    for (int off = 32; off > 0; off >>= 1) part += __shfl_down(part, off, 64);
    if ((tid & 63) == 0) s_red[tid >> 6] = part;
    __syncthreads();
    if (tid == 0){
        float r = 0.f;
#pragma unroll
        for (int wv = 0; wv < 8; wv++) r += s_red[wv];
        out[b] = r;
    }
}

extern "C" void kernel_launch(void* const* d_in, const int* in_sizes, int n_in,
                              void* d_out, int out_size, void* d_ws, size_t ws_size,
                              hipStream_t stream)
{
    jastrow_kernel<<<NB, 512, 0, stream>>>(
        (const float*)d_in[0],  (const float*)d_in[1],  (const float*)d_in[2],
        (const float*)d_in[3],  (const float*)d_in[4],  (const float*)d_in[5],
        (const float*)d_in[6],  (const float*)d_in[7],  (const float*)d_in[8],
        (const float*)d_in[9],  (const float*)d_in[10], (const float*)d_in[11],
        (const float*)d_in[12], (float*)d_out);
}

// Round 3
// 157.827 us; speedup vs baseline: 1.2336x; 1.2336x over previous
//
#include <hip/hip_runtime.h>
#include <hip/hip_bf16.h>
#include <cstddef>

// JastrowNet split into two kernels:
// K1 (filters): one thread per edge row; loads features ONCE, computes both
//   layers' filter MLPs. Layer-1 output is reduced directly to z1 (hx1 depends
//   only on spin since x0 = X_emb[spin]); layer-2 filters stored masked as
//   bf16 in workspace; nuclear filters pre-reduced against Y for both layers.
//   Channel (same/anti/nuc) is block-uniform -> LDS weight reads broadcast.
// K2 (update): per-batch sequential part: x1, hx2, z2 = w2.hx2, x2, readout.
//
// Workspace layout (bytes):
//   [0, 8388608)            w2 : bf16 [512][32][32][8]
//   [8388608, +1048576)     z1p: f32 [512][2][32][8]  (partials over j-halves)
//   [+, +524288)            zn1: f32 [512][32][8]
//   [+, +524288)            zn2: f32 [512][32][8]
// total 10,485,760 bytes

#define NB   512
#define NE   32
#define NA   8
#define NF   32
#define NH   16
#define NK   8
#define NEMB 16

__device__ __forceinline__ float ssp(float v){
    return fmaxf(v, 0.f) + __logf(1.f + __expf(-fabsf(v))) - 0.6931471805599453f;
}

// One 32-feature row through 32->16->8 ssp MLP; weights are LDS broadcast.
__device__ __forceinline__ void compute_w(const float4 ev[8],
        const float* __restrict__ sW1, const float* __restrict__ sB1,
        const float* __restrict__ sW2, const float* __restrict__ sB2,
        float w[NK])
{
    float h1[NH];
#pragma unroll
    for (int h = 0; h < NH; h++) h1[h] = sB1[h];
#pragma unroll
    for (int q = 0; q < 8; q++){
        float e4[4] = {ev[q].x, ev[q].y, ev[q].z, ev[q].w};
#pragma unroll
        for (int c = 0; c < 4; c++){
            const float ef = e4[c];
            const float4* w4 = (const float4*)(sW1 + (4*q + c)*NH);
#pragma unroll
            for (int t = 0; t < 4; t++){
                float4 wv = w4[t];
                h1[4*t+0] = fmaf(ef, wv.x, h1[4*t+0]);
                h1[4*t+1] = fmaf(ef, wv.y, h1[4*t+1]);
                h1[4*t+2] = fmaf(ef, wv.z, h1[4*t+2]);
                h1[4*t+3] = fmaf(ef, wv.w, h1[4*t+3]);
            }
        }
    }
#pragma unroll
    for (int h = 0; h < NH; h++) h1[h] = ssp(h1[h]);
    float acc[NK];
#pragma unroll
    for (int k = 0; k < NK; k++) acc[k] = sB2[k];
#pragma unroll
    for (int h = 0; h < NH; h++){
        const float hv = h1[h];
        const float4* w4 = (const float4*)(sW2 + h*NK);
#pragma unroll
        for (int t = 0; t < 2; t++){
            float4 wv = w4[t];
            acc[4*t+0] = fmaf(hv, wv.x, acc[4*t+0]);
            acc[4*t+1] = fmaf(hv, wv.y, acc[4*t+1]);
            acc[4*t+2] = fmaf(hv, wv.z, acc[4*t+2]);
            acc[4*t+3] = fmaf(hv, wv.w, acc[4*t+3]);
        }
    }
#pragma unroll
    for (int k = 0; k < NK; k++) w[k] = ssp(acc[k]);
}

// ---------------- K1: filters ----------------
// grid 2560: p = bid>>9 in [0,4]; p<4 -> elec quadrant (qi=p>>1, qj=p&1),
// p==4 -> nuclear. batch = bid & 511.
extern "C" __global__ void __launch_bounds__(256, 4)
filters_kernel(const float* __restrict__ edges_elec,
               const float* __restrict__ edges_nuc,
               const float* __restrict__ X_emb,
               const float* __restrict__ Yk,
               const float* __restrict__ wW1, const float* __restrict__ wb1,
               const float* __restrict__ wW2, const float* __restrict__ wb2,
               const float* __restrict__ hW,  const float* __restrict__ hb,
               __hip_bfloat16* __restrict__ w2out,
               float* __restrict__ z1p,
               float* __restrict__ zn1, float* __restrict__ zn2)
{
    __shared__ __align__(16) float s_W1[2*NF*NH];   // both layers, one channel
    __shared__ __align__(16) float s_b1[2*NH];
    __shared__ __align__(16) float s_W2[2*NH*NK];
    __shared__ __align__(16) float s_b2[2*NK];
    __shared__ float s_hx1[2*NK];                   // hx layer1 by spin
    __shared__ float s_Y[NA*NK];

    const int bid = blockIdx.x, t = threadIdx.x;
    const int p = bid >> 9, b = bid & 511;
    const bool isNuc = (p == 4);
    const int qi = p >> 1, qj = p & 1;
    const int cc = isNuc ? 2 : ((qi == qj) ? 0 : 1);

    // stage channel-cc weights for both layers
    for (int idx = t; idx < 2*NF*NH; idx += 256){
        int l = idx >> 9, r = idx & 511;
        s_W1[idx] = wW1[(l*3 + cc)*NF*NH + r];
    }
    if (t < 2*NH*NK){
        int l = t >> 7, r = t & 127;
        s_W2[t] = wW2[(l*3 + cc)*NH*NK + r];
    }
    if (t < 2*NH){ int l = t >> 4, r = t & 15; s_b1[t] = wb1[(l*3 + cc)*NH + r]; }
    if (t < 2*NK){ int l = t >> 3, r = t & 7;  s_b2[t] = wb2[(l*3 + cc)*NK + r]; }
    if (isNuc){
        if (t < NA*NK) s_Y[t] = Yk[t];
    } else if (t < 2*NK){
        // hx1[s,k] = ssp(X_emb[s]@hW[0] + hb[0]) -- spin-only
        int s = t >> 3, k = t & 7;
        float acc = hb[k];
#pragma unroll
        for (int e = 0; e < NEMB; e++)
            acc = fmaf(X_emb[s*NEMB + e], hW[e*NK + k], acc);
        s_hx1[t] = ssp(acc);
    }
    __syncthreads();

    // load this thread's feature row (once, reused for both layers)
    const float* src;
    if (isNuc) src = edges_nuc + ((size_t)b*NE*NA + t) * NF;
    else {
        int i = qi*16 + (t >> 4), j = qj*16 + (t & 15);
        src = edges_elec + ((size_t)b*NE*NE + i*NE + j) * NF;
    }
    float4 ev[8];
    {
        const float4* p4 = (const float4*)src;
#pragma unroll
        for (int q = 0; q < 8; q++) ev[q] = p4[q];
    }

    // ---- layer 1: reduce directly ----
    {
        float w[NK];
        compute_w(ev, s_W1, s_b1, s_W2, s_b2, w);
        if (isNuc){
            const int m = t & 7, i = t >> 3;
            float pk[NK];
#pragma unroll
            for (int k = 0; k < NK; k++) pk[k] = w[k] * s_Y[m*NK + k];
#pragma unroll
            for (int off = 4; off > 0; off >>= 1)
#pragma unroll
                for (int k = 0; k < NK; k++) pk[k] += __shfl_down(pk[k], off, 8);
            if (m == 0){
#pragma unroll
                for (int k = 0; k < NK; k++) zn1[((size_t)b*NE + i)*NK + k] = pk[k];
            }
        } else {
            const int i16 = t >> 4, j16 = t & 15;
            const float msk = (cc == 0 && i16 == j16) ? 0.f : 1.f;
            float pk[NK];
#pragma unroll
            for (int k = 0; k < NK; k++) pk[k] = w[k] * msk * s_hx1[qj*NK + k];
#pragma unroll
            for (int off = 8; off > 0; off >>= 1)
#pragma unroll
                for (int k = 0; k < NK; k++) pk[k] += __shfl_down(pk[k], off, 16);
            if (j16 == 0){
                const int i = qi*16 + i16;
#pragma unroll
                for (int k = 0; k < NK; k++)
                    z1p[(((size_t)b*2 + qj)*NE + i)*NK + k] = pk[k];
            }
        }
    }
    // ---- layer 2: store w (elec, bf16) / reduce (nuc) ----
    {
        float w[NK];
        compute_w(ev, s_W1 + NF*NH, s_b1 + NH, s_W2 + NH*NK, s_b2 + NK, w);
        if (isNuc){
            const int m = t & 7, i = t >> 3;
            float pk[NK];
#pragma unroll
            for (int k = 0; k < NK; k++) pk[k] = w[k] * s_Y[m*NK + k];
#pragma unroll
            for (int off = 4; off > 0; off >>= 1)
#pragma unroll
                for (int k = 0; k < NK; k++) pk[k] += __shfl_down(pk[k], off, 8);
            if (m == 0){
#pragma unroll
                for (int k = 0; k < NK; k++) zn2[((size_t)b*NE + i)*NK + k] = pk[k];
            }
        } else {
            const int i16 = t >> 4, j16 = t & 15;
            const float msk = (cc == 0 && i16 == j16) ? 0.f : 1.f;
            const int i = qi*16 + i16, j = qj*16 + j16;
            union { __hip_bfloat16 h[8]; uint4 u; } pack;
#pragma unroll
            for (int k = 0; k < NK; k++) pack.h[k] = __float2bfloat16(w[k] * msk);
            *(uint4*)&w2out[((size_t)b*NE*NE + i*NE + j)*NK] = pack.u;
        }
    }
}

// ---------------- K2: per-batch sequential update ----------------
extern "C" __global__ void __launch_bounds__(256, 4)
update_kernel(const float* __restrict__ X_emb,
              const float* __restrict__ hW,  const float* __restrict__ hb,
              const float* __restrict__ gW,  const float* __restrict__ gb,
              const float* __restrict__ orbW,
              const __hip_bfloat16* __restrict__ w2,
              const float* __restrict__ z1p,
              const float* __restrict__ zn1, const float* __restrict__ zn2,
              float* __restrict__ out)
{
    __shared__ float s_x[NE*NEMB];     // 512
    __shared__ float s_z[NE*NK];       // 256
    __shared__ float s_hx[NE*NK];      // 256
    __shared__ float s_gW[2*NK*NEMB];  // 256
    __shared__ float s_gb[2*NEMB];
    __shared__ float s_hW1[NEMB*NK];
    __shared__ float s_hb1[NK];
    __shared__ float s_orb[NEMB];
    __shared__ float s_red[4];

    const int b = blockIdx.x, t = threadIdx.x;

    s_gW[t] = gW[t];
    if (t < 2*NEMB)  s_gb[t]  = gb[t];
    if (t < NEMB*NK) s_hW1[t] = hW[NEMB*NK + t];
    if (t < NK)      s_hb1[t] = hb[NK + t];
    if (t < NEMB)    s_orb[t] = orbW[t];
    // z1[i,k] = partials(qj=0,1) + nuclear
    {
        const int i = t >> 3, k = t & 7;
        s_z[t] = z1p[(((size_t)b*2 + 0)*NE + i)*NK + k]
               + z1p[(((size_t)b*2 + 1)*NE + i)*NK + k]
               + zn1[((size_t)b*NE + i)*NK + k];
    }
    __syncthreads();
    // x1 = x0 + z1 @ gW0 + gb0
#pragma unroll
    for (int q = 0; q < 2; q++){
        const int idx = q*256 + t, i = idx >> 4, e = idx & 15;
        float acc = s_gb[e];
#pragma unroll
        for (int k = 0; k < NK; k++)
            acc = fmaf(s_z[i*NK + k], s_gW[k*NEMB + e], acc);
        s_x[idx] = X_emb[(i >> 4)*NEMB + e] + acc;
    }
    __syncthreads();
    // hx2 = ssp(x1 @ hW1 + hb1)
    {
        const int i = t >> 3, k = t & 7;
        float acc = s_hb1[k];
#pragma unroll
        for (int e = 0; e < NEMB; e++)
            acc = fmaf(s_x[i*NEMB + e], s_hW1[e*NK + k], acc);
        s_hx[t] = ssp(acc);
    }
    __syncthreads();
    // z2[i,k] = sum_j w2[i,j,k]*hx2[j,k]
    {
        const int i16 = t >> 4, j16 = t & 15;
#pragma unroll
        for (int qh = 0; qh < 2; qh++){
            const int i = qh*16 + i16;
            float zacc[NK];
#pragma unroll
            for (int k = 0; k < NK; k++) zacc[k] = 0.f;
#pragma unroll
            for (int qj = 0; qj < 2; qj++){
                const int j = qj*16 + j16;
                union { uint4 u; __hip_bfloat16 h[8]; } raw;
                raw.u = *(const uint4*)&w2[((size_t)b*NE*NE + i*NE + j)*NK];
                float pk[NK];
#pragma unroll
                for (int k = 0; k < NK; k++)
                    pk[k] = __bfloat162float(raw.h[k]) * s_hx[j*NK + k];
#pragma unroll
                for (int off = 8; off > 0; off >>= 1)
#pragma unroll
                    for (int k = 0; k < NK; k++) pk[k] += __shfl_down(pk[k], off, 16);
#pragma unroll
                for (int k = 0; k < NK; k++) zacc[k] += pk[k];
            }
            if (j16 == 0){
#pragma unroll
                for (int k = 0; k < NK; k++) s_z[i*NK + k] = zacc[k];
            }
        }
    }
    __syncthreads();
    { const int i = t >> 3, k = t & 7; s_z[t] += zn2[((size_t)b*NE + i)*NK + k]; }
    __syncthreads();
    // x2 = x1 + z2 @ gW1 + gb1
#pragma unroll
    for (int q = 0; q < 2; q++){
        const int idx = q*256 + t, i = idx >> 4, e = idx & 15;
        float acc = s_gb[NEMB + e];
#pragma unroll
        for (int k = 0; k < NK; k++)
            acc = fmaf(s_z[i*NK + k], s_gW[NK*NEMB + k*NEMB + e], acc);
        s_x[idx] += acc;
    }
    __syncthreads();
    // readout
    float part = (s_x[t] + s_x[t + 256]) * s_orb[t & 15];
#pragma unroll
    for (int off = 32; off > 0; off >>= 1) part += __shfl_down(part, off, 64);
    if ((t & 63) == 0) s_red[t >> 6] = part;
    __syncthreads();
    if (t == 0) out[b] = s_red[0] + s_red[1] + s_red[2] + s_red[3];
}

extern "C" void kernel_launch(void* const* d_in, const int* in_sizes, int n_in,
                              void* d_out, int out_size, void* d_ws, size_t ws_size,
                              hipStream_t stream)
{
    const float* edges_elec = (const float*)d_in[0];
    const float* edges_nuc  = (const float*)d_in[1];
    const float* X_emb      = (const float*)d_in[2];
    const float* Yk         = (const float*)d_in[3];
    const float* wW1        = (const float*)d_in[4];
    const float* wb1        = (const float*)d_in[5];
    const float* wW2        = (const float*)d_in[6];
    const float* wb2        = (const float*)d_in[7];
    const float* hW         = (const float*)d_in[8];
    const float* hb         = (const float*)d_in[9];
    const float* gW         = (const float*)d_in[10];
    const float* gb         = (const float*)d_in[11];
    const float* orbW       = (const float*)d_in[12];

    char* ws = (char*)d_ws;
    __hip_bfloat16* w2 = (__hip_bfloat16*)ws;                     // 8,388,608 B
    float* z1p = (float*)(ws + 8388608);                          // 1,048,576 B
    float* zn1 = (float*)(ws + 8388608 + 1048576);                //   524,288 B
    float* zn2 = (float*)(ws + 8388608 + 1048576 + 524288);       //   524,288 B

    filters_kernel<<<5*NB, 256, 0, stream>>>(
        edges_elec, edges_nuc, X_emb, Yk, wW1, wb1, wW2, wb2, hW, hb,
        w2, z1p, zn1, zn2);
    update_kernel<<<NB, 256, 0, stream>>>(
        X_emb, hW, hb, gW, gb, orbW, w2, z1p, zn1, zn2, (float*)d_out);
}